// Round 3
// baseline (60.318 us; speedup 1.0000x reference)
//
#include <hip/hip_runtime.h>

// Problem constants (B=2, C=32, H=W=64, P=3, D=7, K=4)
constexpr int NPIX = 2 * 64 * 64;   // 8192 pixels
constexpr float EPSF = 1e-12f;

// ws layout (floats):
constexpr int WS_WGT  = 0;          // 8192*288, layout [pix][j*32 + c]
constexpr int WS_SIM  = 2359296;    // 8192*64,  [pix][uv], raw 3x3 box-dot
constexpr int WS_F1T  = 2883584;    // 8192*32,  [b,y,x][c] transposed ftm1
constexpr int WS_RBN  = 3145728;    // 8192,     1/max(||patch(ftm1)||,eps)
constexpr int WS_NEED = 3153920;

// ---------------------------------------------------------------------------
// Fused pre-pass: three independent block roles in one dispatch.
//   bx <  512 : wgt  (per-pixel 288-dim projection, wave-uniform weights)
//   bx <  576 : prep (rBN + transposed ftm1)
//   else      : sim  (raw 3x3 box-dot for one (b, uv, 8-row band))
// ---------------------------------------------------------------------------
__global__ __launch_bounds__(256) void fused_pre(
    const float* __restrict__ ft, const float* __restrict__ ftm1,
    const float* __restrict__ wproj_w, const float* __restrict__ wproj_b,
    float* __restrict__ ws)
{
    __shared__ float smem[64 * 73];   // wgt: [px][73]; prep: [4][66]; sim: [10][64]
    const int bx = blockIdx.x;
    const int t  = threadIdx.x;

    if (bx < 512) {
        // ---------------- wgt role ----------------
        const int ogq  = bx & 3;           // output quarter (72 outputs)
        const int base = (bx >> 2) << 6;   // 64 consecutive pixels = one row
        const int b = base >> 12, y = (base >> 6) & 63;
        const int lane = t & 63, wv = t >> 6;
        const int x = lane;

        float cat[64];
        {
            const float* ftb = ft   + ((size_t)b << 17) + (y << 6) + x;
            const float* f1b = ftm1 + ((size_t)b << 17) + (y << 6) + x;
            #pragma unroll
            for (int c = 0; c < 32; ++c) cat[c] = ftb[(size_t)c << 12];
            #pragma unroll
            for (int c = 0; c < 32; ++c) cat[32 + c] = f1b[(size_t)c << 12];
        }
        // wave-uniform output group -> scalar/broadcast weight loads
        const int og = __builtin_amdgcn_readfirstlane(ogq * 4 + wv);
        const float4* w4 = reinterpret_cast<const float4*>(wproj_w);

        #pragma unroll 3
        for (int j = 0; j < 18; ++j) {
            const int o = og * 18 + j;
            float a = wproj_b[o];
            #pragma unroll
            for (int i4 = 0; i4 < 16; ++i4) {
                float4 w = w4[o * 16 + i4];
                a += w.x * cat[i4 * 4]     + w.y * cat[i4 * 4 + 1]
                   + w.z * cat[i4 * 4 + 2] + w.w * cat[i4 * 4 + 3];
            }
            smem[x * 73 + wv * 18 + j] = a;   // odd stride: conflict-free
        }
        __syncthreads();

        float* wgt = ws + WS_WGT;
        for (int idx = t; idx < 64 * 72; idx += 256) {
            int px = idx / 72, oo = idx - px * 72;
            int o = ogq * 72 + oo;            // logical output = c*9 + j
            int c = o / 9, jj = o - c * 9;
            wgt[(size_t)(base + px) * 288 + jj * 32 + c] = smem[px * 73 + oo];
        }
    } else if (bx < 576) {
        // ---------------- prep role ----------------
        const int pb = bx - 512;             // 0..63 : (b, 2-row band)
        const int b = pb >> 5, y0 = (pb & 31) << 1;
        const int r = t >> 6, x = t & 63;
        const int a = y0 - 1 + r;
        const float* f1b = ftm1 + ((size_t)b << 17);

        float n = 0.f;
        if ((unsigned)a < 64u) {
            const int off = (a << 6) + x;
            float4* tdst = reinterpret_cast<float4*>(ws + WS_F1T)
                         + ((size_t)((b << 12) + off) << 3);
            #pragma unroll
            for (int c4 = 0; c4 < 8; ++c4) {
                float4 q;
                q.x = f1b[((size_t)(c4 * 4 + 0) << 12) + off];
                q.y = f1b[((size_t)(c4 * 4 + 1) << 12) + off];
                q.z = f1b[((size_t)(c4 * 4 + 2) << 12) + off];
                q.w = f1b[((size_t)(c4 * 4 + 3) << 12) + off];
                n += q.x * q.x + q.y * q.y + q.z * q.z + q.w * q.w;
                tdst[c4] = q;
            }
        }
        float* nb = smem;                    // [4][66]
        if (x == 0)  nb[r * 66 + 0]  = 0.f;
        if (x == 63) nb[r * 66 + 65] = 0.f;
        nb[r * 66 + x + 1] = n;
        __syncthreads();

        if (r == 1 || r == 2) {
            const int yy = y0 + r - 1;
            float bn = 0.f;
            #pragma unroll
            for (int i = 0; i < 3; ++i)
                #pragma unroll
                for (int j = 0; j < 3; ++j)
                    bn += nb[(r - 1 + i) * 66 + x + j];
            (ws + WS_RBN)[(b << 12) + (yy << 6) + x] = 1.0f / fmaxf(sqrtf(bn), EPSF);
        }
    } else {
        // ---------------- sim role ----------------
        const int sb = bx - 576;             // 0..783
        const int b = sb / 392;
        const int rem = sb - b * 392;
        const int uv = rem % 49;
        const int band = rem / 49;           // 0..7
        const int u = uv / 7 - 3, v = uv % 7 - 3;
        const int y0 = band << 3;
        const int lane = t & 63, wv = t >> 6;
        const float* ftb = ft   + ((size_t)b << 17);
        const float* f1b = ftm1 + ((size_t)b << 17);
        float* sbuf = smem;                  // [10][64]

        for (int r = wv; r < 10; r += 4) {
            const int a = y0 - 1 + r;
            const int brow = a + u, bcol = lane + v;
            float s = 0.f;
            if ((unsigned)a < 64u && (unsigned)brow < 64u && (unsigned)bcol < 64u) {
                const float* pa  = ftb + (a << 6) + lane;
                const float* pbb = f1b + (brow << 6) + bcol;
                float s0 = 0.f, s1 = 0.f, s2 = 0.f, s3 = 0.f;
                #pragma unroll
                for (int c = 0; c < 32; c += 4) {
                    s0 += pa[(size_t)(c + 0) << 12] * pbb[(size_t)(c + 0) << 12];
                    s1 += pa[(size_t)(c + 1) << 12] * pbb[(size_t)(c + 1) << 12];
                    s2 += pa[(size_t)(c + 2) << 12] * pbb[(size_t)(c + 2) << 12];
                    s3 += pa[(size_t)(c + 3) << 12] * pbb[(size_t)(c + 3) << 12];
                }
                s = (s0 + s1) + (s2 + s3);
            }
            sbuf[r * 64 + lane] = s;
        }
        __syncthreads();

        float* simb = ws + WS_SIM;
        for (int yl = wv; yl < 8; yl += 4) {
            const int yy = y0 + yl;
            const int x = lane;
            const int cy = yy + u, cx = x + v;
            float dot = 0.f;
            if ((unsigned)cy < 64u && (unsigned)cx < 64u) {
                #pragma unroll
                for (int i = 0; i < 3; ++i) {
                    float rs = sbuf[(yl + i) * 64 + x];
                    if (x > 0)  rs += sbuf[(yl + i) * 64 + x - 1];
                    if (x < 63) rs += sbuf[(yl + i) * 64 + x + 1];
                    dot += rs;
                }
            }
            simb[(size_t)(((b << 12) + (yy << 6) + x) << 6) + uv] = dot;
        }
    }
}

// ---------------------------------------------------------------------------
// Gather: top-4 over dot*rBN(center), gather via transposed ftm1, aggregate.
// Half-wave (32 lanes = 32 channels) per pixel; block = 8 pixels (same row).
// ---------------------------------------------------------------------------
__global__ __launch_bounds__(256) void gather_kernel(
    const float* __restrict__ ws, const float* __restrict__ agg_w,
    const float* __restrict__ agg_bp, float* __restrict__ out)
{
    const float* wgt    = ws + WS_WGT;
    const float* simb   = ws + WS_SIM;
    const float* ftm1_t = ws + WS_F1T;
    const float* rBN    = ws + WS_RBN;

    __shared__ float obuf[4][64];
    const int lane = threadIdx.x & 63;
    const int wv = threadIdx.x >> 6;
    const int half = lane >> 5;
    const int c = lane & 31;
    const int pix0 = blockIdx.x << 3;
    const int pix = pix0 + (wv << 1) + half;
    const int b = pix >> 12, y = (pix >> 6) & 63, x = pix & 63;

    // ---- top-4 keys: dot * rBN(center); OOB center stored dot==0 -> key 0 ----
    const float* sp = simb + ((size_t)pix << 6);
    float s0, s1;
    {
        const int d0 = c;
        int cy = y + d0 / 7 - 3, cx = x + d0 % 7 - 3;
        int cyc = min(max(cy, 0), 63), cxc = min(max(cx, 0), 63);
        s0 = sp[d0] * rBN[(b << 12) + (cyc << 6) + cxc];
        const int d1 = c + 32;
        if (d1 < 49) {
            int cy1 = y + d1 / 7 - 3, cx1 = x + d1 % 7 - 3;
            int cy1c = min(max(cy1, 0), 63), cx1c = min(max(cx1, 0), 63);
            s1 = sp[d1] * rBN[(b << 12) + (cy1c << 6) + cx1c];
        } else s1 = -3.0e38f;
    }
    int chosen[4];
    #pragma unroll
    for (int k = 0; k < 4; ++k) {
        float bs; int bi;
        if (s0 >= s1) { bs = s0; bi = c; }
        else          { bs = s1; bi = c + 32; }
        #pragma unroll
        for (int off = 16; off; off >>= 1) {   // stays within the half-wave
            float os = __shfl_xor(bs, off, 64);
            int   oi = __shfl_xor(bi, off, 64);
            if (os > bs || (os == bs && oi < bi)) { bs = os; bi = oi; }
        }
        chosen[k] = bi;
        if (bi == c)           s0 = -3.0e38f;
        else if (bi == c + 32) s1 = -3.0e38f;
    }

    // ---- gather + aggregate ----
    float aw[4];
    aw[0] = agg_w[0]; aw[1] = agg_w[1]; aw[2] = agg_w[2]; aw[3] = agg_w[3];
    const float ab = agg_bp[0];

    int cyv[4], cxv[4]; bool cval[4];
    #pragma unroll
    for (int k = 0; k < 4; ++k) {
        int d = chosen[k];
        int di = d / 7, dj = d - di * 7;
        int cy = y + di - 3, cx = x + dj - 3;
        cval[k] = ((unsigned)cy < 64u) && ((unsigned)cx < 64u);
        cyv[k] = cy; cxv[k] = cx;
    }

    float outc = 0.f;
    const float* wp = wgt + (size_t)pix * 288 + c;   // [j*32 + c]
    #pragma unroll
    for (int pi = 0; pi < 3; ++pi) {
        #pragma unroll
        for (int pj = 0; pj < 3; ++pj) {
            float g = ab;
            #pragma unroll
            for (int k = 0; k < 4; ++k) {
                int row = cyv[k] + pi - 1, col = cxv[k] + pj - 1;
                float vv = 0.f;
                if (cval[k] && (unsigned)row < 64u && (unsigned)col < 64u)
                    vv = ftm1_t[((size_t)((b << 12) + (row << 6) + col) << 5) + c];
                g += aw[k] * vv;
            }
            outc += wp[(pi * 3 + pj) << 5] * g;      // coalesced weight read
        }
    }
    obuf[wv][lane] = outc;
    __syncthreads();

    {
        const int cc = threadIdx.x >> 3;   // 0..31
        const int px = threadIdx.x & 7;    // 0..7
        const float vv = obuf[px >> 1][((px & 1) << 5) + cc];
        const int bb = pix0 >> 12, yy = (pix0 >> 6) & 63, xx0 = pix0 & 63;
        out[((size_t)((bb << 5) + cc) << 12) + (yy << 6) + xx0 + px] = vv;
    }
}

// ---------------------------------------------------------------------------
// Fallback (no workspace): monolithic wave-per-pixel kernel (rounds 1-2).
// ---------------------------------------------------------------------------
__global__ __launch_bounds__(256) void agg_fallback(
    const float* __restrict__ feat_t, const float* __restrict__ feat_tm1,
    const float* __restrict__ agg_w, const float* __restrict__ agg_bp,
    const float* __restrict__ wproj_w, const float* __restrict__ wproj_b,
    float* __restrict__ out)
{
    __shared__ __align__(16) float tile[4][2592];
    __shared__ __align__(16) float qbuf[4][384];
    __shared__ __align__(16) float catb[4][64];

    const int lane = threadIdx.x & 63;
    const int wv   = threadIdx.x >> 6;
    const int pix  = blockIdx.x * 4 + wv;
    const int b = pix >> 12;
    const int y = (pix >> 6) & 63;
    const int x = pix & 63;
    float* tl = tile[wv];
    float* qb = qbuf[wv];

    const float* ftm1_b = feat_tm1 + ((size_t)b << 17);
    const float* ft_b   = feat_t   + ((size_t)b << 17);

    for (int idx = lane; idx < 2592; idx += 64) {
        int c = idx / 81, r = idx - c * 81;
        int ty = r / 9,  tx = r - ty * 9;
        int gy = y - 4 + ty, gx = x - 4 + tx;
        float v = 0.f;
        if ((unsigned)gy < 64u && (unsigned)gx < 64u)
            v = ftm1_b[(c << 12) + (gy << 6) + gx];
        tl[idx] = v;
    }

    float qv[5];
    float qp = 0.f;
    {
        int qn = 0;
        for (int idx = lane; idx < 288; idx += 64) {
            int c = idx / 9, p = idx - c * 9;
            int pi = p / 3, pj = p - pi * 3;
            int gy = y - 1 + pi, gx = x - 1 + pj;
            float v = 0.f;
            if ((unsigned)gy < 64u && (unsigned)gx < 64u)
                v = ft_b[(c << 12) + (gy << 6) + gx];
            qv[qn++] = v;
            qp += v * v;
        }
    }
    #pragma unroll
    for (int off = 32; off; off >>= 1) qp += __shfl_xor(qp, off, 64);
    const float qinv = 1.0f / fmaxf(sqrtf(qp), EPSF);
    {
        int qn = 0;
        for (int idx = lane; idx < 288; idx += 64) {
            int c = idx / 9, p = idx - c * 9;
            qb[c * 12 + p] = qv[qn++] * qinv;
        }
    }
    catb[wv][lane] = (lane < 32)
        ? ft_b[(lane << 12) + (y << 6) + x]
        : ftm1_b[((lane - 32) << 12) + (y << 6) + x];
    __syncthreads();

    float sim;
    {
        const int d = lane;
        const int di = d / 7, dj = d - di * 7;
        const int cy = y + di - 3, cx = x + dj - 3;
        const bool act = d < 49;
        const bool valid = act && ((unsigned)cy < 64u) && ((unsigned)cx < 64u);
        sim = act ? 0.0f : -3.0e38f;
        if (valid) {
            float dot = 0.f, n2 = 0.f;
            const int base = di * 9 + dj;
            for (int c = 0; c < 32; ++c) {
                const float4 qa = *reinterpret_cast<const float4*>(&qb[c * 12]);
                const float4 qd = *reinterpret_cast<const float4*>(&qb[c * 12 + 4]);
                const float  qe = qb[c * 12 + 8];
                const float* tp = &tl[c * 81 + base];
                float k0 = tp[0],  k1 = tp[1],  k2 = tp[2];
                float k3 = tp[9],  k4 = tp[10], k5 = tp[11];
                float k6 = tp[18], k7 = tp[19], k8 = tp[20];
                dot += qa.x*k0 + qa.y*k1 + qa.z*k2 + qa.w*k3
                     + qd.x*k4 + qd.y*k5 + qd.z*k6 + qd.w*k7 + qe*k8;
                n2  += k0*k0 + k1*k1 + k2*k2 + k3*k3 + k4*k4
                     + k5*k5 + k6*k6 + k7*k7 + k8*k8;
            }
            sim = dot / fmaxf(sqrtf(n2), EPSF);
        }
    }

    int chosen[4];
    {
        float s = sim; int si = lane;
        #pragma unroll
        for (int k = 0; k < 4; ++k) {
            float bs = s; int bi = si;
            #pragma unroll
            for (int off = 1; off < 64; off <<= 1) {
                float os = __shfl_xor(bs, off, 64);
                int   oi = __shfl_xor(bi, off, 64);
                if (os > bs || (os == bs && oi < bi)) { bs = os; bi = oi; }
            }
            chosen[k] = bi;
            if (si == bi) s = -3.0e38f;
        }
    }
    __syncthreads();

    const float ab  = agg_bp[0];
    const float aw0 = agg_w[0], aw1 = agg_w[1], aw2 = agg_w[2], aw3 = agg_w[3];
    int  dbase[4];
    bool dvalid[4];
    #pragma unroll
    for (int k = 0; k < 4; ++k) {
        int dk = chosen[k];
        int di = dk / 7, dj = dk - di * 7;
        int cy = y + di - 3, cx = x + dj - 3;
        dvalid[k] = ((unsigned)cy < 64u) && ((unsigned)cx < 64u);
        dbase[k]  = di * 9 + dj;
    }
    for (int o = lane; o < 288; o += 64) {
        int c = o / 9, p = o - c * 9;
        int pi = p / 3, pj = p - pi * 3;
        int off = c * 81 + pi * 9 + pj;
        float v0 = dvalid[0] ? tl[off + dbase[0]] : 0.f;
        float v1 = dvalid[1] ? tl[off + dbase[1]] : 0.f;
        float v2 = dvalid[2] ? tl[off + dbase[2]] : 0.f;
        float v3 = dvalid[3] ? tl[off + dbase[3]] : 0.f;
        float a = ab + aw0 * v0 + aw1 * v1 + aw2 * v2 + aw3 * v3;
        float wg = wproj_b[o];
        const float4* w4  = reinterpret_cast<const float4*>(wproj_w);
        const float4* cb4 = reinterpret_cast<const float4*>(&catb[wv][0]);
        #pragma unroll
        for (int i4 = 0; i4 < 16; ++i4) {
            float4 wv4 = w4[o * 16 + i4];
            float4 cv  = cb4[i4];
            wg += wv4.x*cv.x + wv4.y*cv.y + wv4.z*cv.z + wv4.w*cv.w;
        }
        qb[c * 12 + p] = a * wg;
    }
    __syncthreads();

    if (lane < 32) {
        const float* qq = &qb[lane * 12];
        float sum = (((qq[0]+qq[1]) + (qq[2]+qq[3])) + ((qq[4]+qq[5]) + (qq[6]+qq[7]))) + qq[8];
        out[((size_t)b << 17) + (lane << 12) + (y << 6) + x] = sum;
    }
}

// ---------------------------------------------------------------------------
extern "C" void kernel_launch(void* const* d_in, const int* in_sizes, int n_in,
                              void* d_out, int out_size, void* d_ws, size_t ws_size,
                              hipStream_t stream)
{
    const float* feat_t   = (const float*)d_in[0];
    const float* feat_tm1 = (const float*)d_in[1];
    const float* agg_w    = (const float*)d_in[2];
    const float* agg_b    = (const float*)d_in[3];
    const float* wproj_w  = (const float*)d_in[4];
    const float* wproj_b  = (const float*)d_in[5];
    float* outp = (float*)d_out;

    const size_t need = (size_t)WS_NEED * sizeof(float);
    if (ws_size >= need) {
        float* ws = (float*)d_ws;
        fused_pre<<<576 + 784, 256, 0, stream>>>(feat_t, feat_tm1, wproj_w, wproj_b, ws);
        gather_kernel<<<NPIX / 8, 256, 0, stream>>>(ws, agg_w, agg_b, outp);
    } else {
        agg_fallback<<<NPIX / 4, 256, 0, stream>>>(feat_t, feat_tm1, agg_w, agg_b,
                                                   wproj_w, wproj_b, outp);
    }
}